// Round 16
// baseline (552.102 us; speedup 1.0000x reference)
//
#include <hip/hip_runtime.h>
#include <hip/hip_bf16.h>
#include <math.h>
#include <string.h>

#define HID 32
#define PSHIFT 8                 // dst bucket = dst >> 8 (256 nodes/bucket)
#define NPB (1 << PSHIFT)
#define MAXP 512                 // partition scan width (supports N <= 131072)
#define SLOTS 17408              // per-bucket staging; mean 16384, +8 sigma (guarded)
#define GS 32                    // gcur stride in ints: 1 counter per 128B cacheline
#define HS_ROWS 32               // hsum partial rows (spread atomic contention)
#define COLBUF 3072              // mlp_fused col slice; 32 nodes, mean 2048 (guarded)
#define COLBUF0 6144             // mlp0 col slice; 64 nodes, mean 4096 (guarded)
typedef unsigned short u16;
typedef unsigned char u8;
typedef float f32x2 __attribute__((ext_vector_type(2)));

// ---------- fp8 e4m3 helpers (OCP; non-negative activations) ----------
__device__ inline float e42f_sw(unsigned b) {
    unsigned u = (b & 0x7fu) << 20;
    float f; memcpy(&f, &u, 4);
    return f * 0x1p120f;
}
__device__ inline unsigned f2e4_sw(float f) {
    f = fminf(f, 448.f);
    float y = f * 0x1p-120f;
    unsigned r; memcpy(&r, &y, 4);
    r = r + 0x7FFFFu + ((r >> 20) & 1u);
    return (r >> 20) & 0x7fu;
}
__device__ inline void acc_e4(float* a, unsigned w) {
#if __has_builtin(__builtin_amdgcn_cvt_pk_f32_fp8)
    f32x2 lo = __builtin_amdgcn_cvt_pk_f32_fp8(w, false);
    f32x2 hi = __builtin_amdgcn_cvt_pk_f32_fp8(w, true);
    a[0] += lo.x; a[1] += lo.y; a[2] += hi.x; a[3] += hi.y;
#else
    a[0] += e42f_sw(w);
    a[1] += e42f_sw(w >> 8);
    a[2] += e42f_sw(w >> 16);
    a[3] += e42f_sw(w >> 24);
#endif
}
__device__ inline unsigned pack_e4(float o0, float o1, float o2, float o3) {
#if __has_builtin(__builtin_amdgcn_cvt_pk_fp8_f32)
    unsigned pw = (unsigned)__builtin_amdgcn_cvt_pk_fp8_f32(
        fminf(o0, 448.f), fminf(o1, 448.f), 0, false);
    pw = (unsigned)__builtin_amdgcn_cvt_pk_fp8_f32(
        fminf(o2, 448.f), fminf(o3, 448.f), pw, true);
    return pw;
#else
    return f2e4_sw(o0) | (f2e4_sw(o1) << 8) | (f2e4_sw(o2) << 16) | (f2e4_sw(o3) << 24);
#endif
}

// ---------------- zero / init ----------------
__global__ void zero_kernel(float* __restrict__ p, int n) {
    int i = blockIdx.x * blockDim.x + threadIdx.x;
    if (i < n) p[i] = 0.f;
}
__global__ void init_gcur2(int* __restrict__ gA, int* __restrict__ gB, int P) {
    int i = blockIdx.x * blockDim.x + threadIdx.x;
    if (i < P) gA[i * GS] = i * SLOTS;
    else if (i < 2 * P) { int b = i - P; gB[b * GS] = b * SLOTS; }
}

// ---------------- phase 1: partition, ONE LDS-atomic pass (R16) ----------------
// R7-R10: 5 variants flat at ~5.3 cy/edge with all pipes idle -> the two LDS-atomic
// passes (hist + placement) were the serial floor. R16: hist atomic's RETURN VALUE
// is a stable per-wave rank; after converting h[][] to a wave-exclusive prefix,
// final addr = gbase[bk] + wprefix[wid][bk] + pos, stored straight from registers.
// Deletes the placement pass, sortedv/bktid (24KB LDS), and the copy-out loop.
__global__ void partition_edges(const int* __restrict__ srcA, const int* __restrict__ dstA,
                                int* __restrict__ gcurA, unsigned* __restrict__ stagedA,
                                const int* __restrict__ srcB, const int* __restrict__ dstB,
                                int* __restrict__ gcurB, unsigned* __restrict__ stagedB,
                                int gsplit, int E, int P) {
    __shared__ int h[4][MAXP];          // 8 KB wave-private counters -> wave prefix
    __shared__ int gbase[MAXP];         // 2 KB global reservation bases
    __shared__ int wsums[4];
    const int* src; const int* dst; int* gcur; unsigned* staged;
    int bid = blockIdx.x;
    if (bid < gsplit) { src = srcA; dst = dstA; gcur = gcurA; staged = stagedA; }
    else { bid -= gsplit; src = srcB; dst = dstB; gcur = gcurB; staged = stagedB; }

    int t = threadIdx.x, wid = t >> 6, lane = t & 63;
    for (int i = t; i < 4 * MAXP; i += 256) (&h[0][0])[i] = 0;
    __syncthreads();

    int base = bid * 4096;
    int4 S[4], D[4];
    u16 pos[16];
#pragma unroll
    for (int r = 0; r < 4; r++) {
        int e = base + r * 1024 + t * 4;
        if (e + 3 < E) {
            S[r] = *(const int4*)(src + e);
            D[r] = *(const int4*)(dst + e);
        } else {
            int s0[4], d0[4];
            for (int j = 0; j < 4; j++) {
                int ee = e + j;
                s0[j] = (ee < E) ? src[ee] : -1;
                d0[j] = (ee < E) ? dst[ee] : -1;
            }
            S[r] = make_int4(s0[0], s0[1], s0[2], s0[3]);
            D[r] = make_int4(d0[0], d0[1], d0[2], d0[3]);
        }
        // single LDS-atomic pass: rank within wave for this bucket
        if (D[r].x >= 0) pos[r*4+0] = (u16)atomicAdd(&h[wid][D[r].x >> PSHIFT], 1);
        if (D[r].y >= 0) pos[r*4+1] = (u16)atomicAdd(&h[wid][D[r].y >> PSHIFT], 1);
        if (D[r].z >= 0) pos[r*4+2] = (u16)atomicAdd(&h[wid][D[r].z >> PSHIFT], 1);
        if (D[r].w >= 0) pos[r*4+3] = (u16)atomicAdd(&h[wid][D[r].w >> PSHIFT], 1);
    }
    __syncthreads();

    // per-bucket totals -> global reservation; convert h[w][bk] to wave-excl prefix
    int b0 = 2 * t, b1 = 2 * t + 1;
    if (b0 < P) {
        int c0 = h[0][b0], c1 = h[1][b0], c2 = h[2][b0], c3 = h[3][b0];
        int tot = c0 + c1 + c2 + c3;
        if (tot) gbase[b0] = atomicAdd(&gcur[b0 * GS], tot);
        h[0][b0] = 0; h[1][b0] = c0; h[2][b0] = c0 + c1; h[3][b0] = c0 + c1 + c2;
    }
    if (b1 < P) {
        int c0 = h[0][b1], c1 = h[1][b1], c2 = h[2][b1], c3 = h[3][b1];
        int tot = c0 + c1 + c2 + c3;
        if (tot) gbase[b1] = atomicAdd(&gcur[b1 * GS], tot);
        h[0][b1] = 0; h[1][b1] = c0; h[2][b1] = c0 + c1; h[3][b1] = c0 + c1 + c2;
    }
    __syncthreads();

    // write pass: straight from registers into per-block bucket runs
#pragma unroll
    for (int r = 0; r < 4; r++) {
        int ss[4] = { S[r].x, S[r].y, S[r].z, S[r].w };
        int dd[4] = { D[r].x, D[r].y, D[r].z, D[r].w };
#pragma unroll
        for (int j = 0; j < 4; j++) {
            int d = dd[j];
            if (d >= 0) {
                int bk = d >> PSHIFT;
                int addr = gbase[bk] + h[wid][bk] + (int)pos[r*4+j];
                if (addr < (bk + 1) * SLOTS)     // overflow guard
                    staged[addr] = ((unsigned)(d & (NPB - 1)) << 17) | (unsigned)ss[j];
            }
        }
    }
}

// ---------------- phase 2: bucket-count scan; block per graph ----------------
__global__ void scan_buckets(const int* __restrict__ gcurA, int* __restrict__ colbaseA,
                             int* __restrict__ rowptrA,
                             const int* __restrict__ gcurB, int* __restrict__ colbaseB,
                             int* __restrict__ rowptrB, int P, int N) {
    __shared__ int wsums[4];
    const int* gcur; int* colbase; int* rowptr;
    if (blockIdx.x == 0) { gcur = gcurA; colbase = colbaseA; rowptr = rowptrA; }
    else { gcur = gcurB; colbase = colbaseB; rowptr = rowptrB; }
    int t = threadIdx.x, wid = t >> 6, lane = t & 63;
    int b0 = 2 * t, b1 = 2 * t + 1;
    int c0 = 0, c1 = 0;
    if (b0 < P) { c0 = gcur[b0 * GS] - b0 * SLOTS; if (c0 > SLOTS) c0 = SLOTS; }
    if (b1 < P) { c1 = gcur[b1 * GS] - b1 * SLOTS; if (c1 > SLOTS) c1 = SLOTS; }
    int s = c0 + c1;
    int incl = s;
#pragma unroll
    for (int off = 1; off < 64; off <<= 1) {
        int u = __shfl_up(incl, off, 64);
        if (lane >= off) incl += u;
    }
    if (lane == 63) wsums[wid] = incl;
    __syncthreads();
    int woff = 0;
#pragma unroll
    for (int w = 0; w < 4; w++) if (w < wid) woff += wsums[w];
    int excl = woff + incl - s;
    if (b0 < P) colbase[b0] = excl;
    if (b1 < P) colbase[b1] = excl + c0;
    if (t == 255) {
        colbase[P] = excl + s;
        rowptr[N]  = excl + s;
    }
}

// ---------------- phase 3: per-bucket counting sort, LDS-staged writeout ---------
// R15 (kept): dst_local-only key; LDS sorted[] staging so the col writeout is
// CONTIGUOUS (direct-global variant thrashed: 289MB HBM writes, R14).
__global__ void sort_bucket(const unsigned* __restrict__ stagedA, const int* __restrict__ gcurA,
                            const int* __restrict__ colbaseA, int* __restrict__ rowptrA,
                            int* __restrict__ colA,
                            const unsigned* __restrict__ stagedB, const int* __restrict__ gcurB,
                            const int* __restrict__ colbaseB, int* __restrict__ rowptrB,
                            int* __restrict__ colB,
                            int gsplit, int N) {
    __shared__ int cnt[NPB];            // 1 KB
    __shared__ int wsum[4];
    __shared__ int sorted[SLOTS];       // 68 KB
    const unsigned* staged; const int* gcur; const int* colbase; int* rowptr; int* col;
    int b = blockIdx.x;
    if (b < gsplit) { staged = stagedA; gcur = gcurA; colbase = colbaseA; rowptr = rowptrA; col = colA; }
    else { b -= gsplit; staged = stagedB; gcur = gcurB; colbase = colbaseB; rowptr = rowptrB; col = colB; }
    int t = threadIdx.x, lane = t & 63, wid = t >> 6;
    int sBeg = b * SLOTS;
    int sEnd = gcur[b * GS]; if (sEnd > sBeg + SLOTS) sEnd = sBeg + SLOTS;
    int total = sEnd - sBeg;
    int colStart = colbase[b];
    int nodeBase = b << PSHIFT;

    cnt[t] = 0;                          // NPB == 256 == blockDim
    __syncthreads();
    for (int i = sBeg + t; i < sEnd; i += 256)
        atomicAdd(&cnt[staged[i] >> 17], 1);
    __syncthreads();

    int myc = cnt[t];
    int incl = myc;
#pragma unroll
    for (int off = 1; off < 64; off <<= 1) {
        int u = __shfl_up(incl, off, 64);
        if (lane >= off) incl += u;
    }
    if (lane == 63) wsum[wid] = incl;
    __syncthreads();
    int woff = 0;
#pragma unroll
    for (int w = 0; w < 4; w++) if (w < wid) woff += wsum[w];
    int excl = woff + incl - myc;
    int node = nodeBase + t;
    if (node < N) rowptr[node] = colStart + excl;
    __syncthreads();
    cnt[t] = excl;                       // LDS placement cursor for node t
    __syncthreads();

    for (int i = sBeg + t; i < sEnd; i += 256) {
        unsigned w = staged[i];
        int pos = atomicAdd(&cnt[w >> 17], 1);
        sorted[pos] = (int)(w & 0x1FFFFu);
    }
    __syncthreads();
    for (int i = t; i < total; i += 256)   // contiguous coalesced writeout
        col[colStart + i] = sorted[i];
}

// ---------------- layer 0 fused: gather(d=1) + MLP -> fp8 out (graph-batched) -----
__global__ void mlp0_fused(const int* __restrict__ rowptrA, const int* __restrict__ colA,
                           const float* __restrict__ x0A, u8* __restrict__ outA,
                           const int* __restrict__ rowptrB, const int* __restrict__ colB,
                           const float* __restrict__ x0B, u8* __restrict__ outB,
                           const float* __restrict__ W1, const float* __restrict__ b1,
                           const float* __restrict__ W2, const float* __restrict__ b2,
                           int gsplit, int n) {
    __shared__ float sW1[HID], sb1[HID], sW2[HID * HID], sb2[HID];
    __shared__ int colbuf[COLBUF0];
    const int* rowptr; const int* col; const float* x0; u8* out;
    int bid = blockIdx.x;
    if (bid < gsplit) { rowptr = rowptrA; col = colA; x0 = x0A; out = outA; }
    else { bid -= gsplit; rowptr = rowptrB; col = colB; x0 = x0B; out = outB; }
    int t = threadIdx.x;
    if (t < HID) { sW1[t] = W1[t]; sb1[t] = b1[t]; sb2[t] = b2[t]; }
    for (int i = t; i < HID * HID; i += blockDim.x) sW2[i] = W2[i];

    int firstNode = bid * 64;
    int lastNode  = firstNode + 64; if (lastNode > n) lastNode = n;
    int blockStart = (firstNode < n) ? rowptr[firstNode] : 0;
    int blockEnd   = (firstNode < n) ? rowptr[lastNode] : 0;
    int stagedCnt = blockEnd - blockStart; if (stagedCnt > COLBUF0) stagedCnt = COLBUF0;
    for (int i = t; i < stagedCnt; i += 256) colbuf[i] = col[blockStart + i];
    __syncthreads();

    int node = firstNode + (t >> 2);
    int q    = t & 3;
    int lane = t & 63;
    int base = lane & ~3;
    bool active = node < n;

    float s = 0.f;
    if (active) {
        int beg = rowptr[node], end = rowptr[node + 1];
        int jSplit = blockStart + stagedCnt; if (jSplit > end) jSplit = end;
        int j = beg + q;
        for (; j + 12 < jSplit; j += 16) {
            int c0 = colbuf[j - blockStart];
            int c1 = colbuf[j + 4 - blockStart];
            int c2 = colbuf[j + 8 - blockStart];
            int c3 = colbuf[j + 12 - blockStart];
            s += x0[c0]; s += x0[c1]; s += x0[c2]; s += x0[c3];
        }
        for (; j < jSplit; j += 4) s += x0[colbuf[j - blockStart]];
        for (; j < end; j += 4) s += x0[col[j]];
    }
    s += __shfl_xor(s, 1, 64);
    s += __shfl_xor(s, 2, 64);
    float v = active ? (x0[node] + s) : 0.f;

    float h[8];
#pragma unroll
    for (int i = 0; i < 8; i++) h[i] = fmaxf(fmaf(v, sW1[q * 8 + i], sb1[q * 8 + i]), 0.f);
    float o[8];
#pragma unroll
    for (int i = 0; i < 8; i++) o[i] = sb2[q * 8 + i];
#pragma unroll
    for (int k = 0; k < HID; k++) {
        float hk = __shfl(h[k & 7], base | (k >> 3), 64);
#pragma unroll
        for (int i = 0; i < 8; i++) o[i] = fmaf(hk, sW2[k * HID + q * 8 + i], o[i]);
    }
    if (active) {
        unsigned w0 = pack_e4(fmaxf(o[0], 0.f), fmaxf(o[1], 0.f),
                              fmaxf(o[2], 0.f), fmaxf(o[3], 0.f));
        unsigned w1 = pack_e4(fmaxf(o[4], 0.f), fmaxf(o[5], 0.f),
                              fmaxf(o[6], 0.f), fmaxf(o[7], 0.f));
        uint2 pk = make_uint2(w0, w1);
        *(uint2*)(out + ((size_t)node << 5) + (q << 3)) = pk;
    }
}

// ---------------- hidden layer fused: fp8 gather + MLP (graph-batched) ----------
template <bool REDUCE>
__global__ void mlp_fused(const int* __restrict__ rowptrA, const int* __restrict__ colA,
                          const u8* __restrict__ xinA, u8* __restrict__ xoutA,
                          float* __restrict__ hsumA,
                          const int* __restrict__ rowptrB, const int* __restrict__ colB,
                          const u8* __restrict__ xinB, u8* __restrict__ xoutB,
                          float* __restrict__ hsumB,
                          const float* __restrict__ W1, const float* __restrict__ b1,
                          const float* __restrict__ W2, const float* __restrict__ b2,
                          int gsplit, int n) {
    __shared__ float sW1[HID * HID], sb1[HID], sW2[HID * HID], sb2[HID];
    __shared__ int colbuf[COLBUF];
    __shared__ float red[4][HID];
    const int* rowptr; const int* col; const u8* xin; u8* xout; float* hsum;
    int bid = blockIdx.x;
    if (bid < gsplit) { rowptr = rowptrA; col = colA; xin = xinA; xout = xoutA; hsum = hsumA; }
    else { bid -= gsplit; rowptr = rowptrB; col = colB; xin = xinB; xout = xoutB; hsum = hsumB; }
    int t = threadIdx.x;
    for (int i = t; i < HID * HID; i += blockDim.x) { sW1[i] = W1[i]; sW2[i] = W2[i]; }
    if (t < HID) { sb1[t] = b1[t]; sb2[t] = b2[t]; }

    int firstNode = bid * 32;
    int lastNode  = firstNode + 32; if (lastNode > n) lastNode = n;
    int blockStart = (firstNode < n) ? rowptr[firstNode] : 0;
    int blockEnd   = (firstNode < n) ? rowptr[lastNode] : 0;
    int stagedCnt = blockEnd - blockStart; if (stagedCnt > COLBUF) stagedCnt = COLBUF;
    for (int i = t; i < stagedCnt; i += 256) colbuf[i] = col[blockStart + i];
    __syncthreads();

    int node = firstNode + (t >> 3);
    int q    = t & 7;
    int lane = t & 63;
    int base = lane & ~7;
    bool active = node < n;

    float va[4];
#pragma unroll
    for (int i = 0; i < 4; i++) va[i] = 0.f;
    if (active) {
        int beg = rowptr[node], end = rowptr[node + 1];
        const u8* xq = xin + (q << 2);
        float a0[4], a1[4], a2[4], a3[4];
#pragma unroll
        for (int i = 0; i < 4; i++) a0[i] = a1[i] = a2[i] = a3[i] = 0.f;
        {   // self term (eps = 0)
            unsigned w = *(const unsigned*)(xq + ((size_t)node << 5));
            acc_e4(a0, w);
        }
        int jSplit = blockStart + stagedCnt; if (jSplit > end) jSplit = end;
        int j = beg;
        for (; j + 8 <= jSplit; j += 8) {
            int lj = j - blockStart;
            int c0 = colbuf[lj+0], c1 = colbuf[lj+1], c2 = colbuf[lj+2], c3 = colbuf[lj+3];
            int c4 = colbuf[lj+4], c5 = colbuf[lj+5], c6 = colbuf[lj+6], c7 = colbuf[lj+7];
            unsigned w0 = *(const unsigned*)(xq + ((size_t)c0 << 5));
            unsigned w1 = *(const unsigned*)(xq + ((size_t)c1 << 5));
            unsigned w2 = *(const unsigned*)(xq + ((size_t)c2 << 5));
            unsigned w3 = *(const unsigned*)(xq + ((size_t)c3 << 5));
            unsigned w4 = *(const unsigned*)(xq + ((size_t)c4 << 5));
            unsigned w5 = *(const unsigned*)(xq + ((size_t)c5 << 5));
            unsigned w6 = *(const unsigned*)(xq + ((size_t)c6 << 5));
            unsigned w7 = *(const unsigned*)(xq + ((size_t)c7 << 5));
            acc_e4(a0, w0); acc_e4(a1, w1); acc_e4(a2, w2); acc_e4(a3, w3);
            acc_e4(a0, w4); acc_e4(a1, w5); acc_e4(a2, w6); acc_e4(a3, w7);
        }
        for (; j < jSplit; j++) {
            unsigned w = *(const unsigned*)(xq + ((size_t)colbuf[j - blockStart] << 5));
            acc_e4(a0, w);
        }
        for (; j < end; j++) {
            unsigned w = *(const unsigned*)(xq + ((size_t)col[j] << 5));
            acc_e4(a0, w);
        }
#pragma unroll
        for (int i = 0; i < 4; i++) va[i] = (a0[i] + a1[i]) + (a2[i] + a3[i]);
    }

    float h[4];
#pragma unroll
    for (int i = 0; i < 4; i++) h[i] = sb1[q * 4 + i];
#pragma unroll
    for (int k = 0; k < HID; k++) {
        float vk = __shfl(va[k & 3], base | (k >> 2), 64);
#pragma unroll
        for (int i = 0; i < 4; i++) h[i] = fmaf(vk, sW1[k * HID + q * 4 + i], h[i]);
    }
#pragma unroll
    for (int i = 0; i < 4; i++) h[i] = fmaxf(h[i], 0.f);

    float o[4];
#pragma unroll
    for (int i = 0; i < 4; i++) o[i] = sb2[q * 4 + i];
#pragma unroll
    for (int k = 0; k < HID; k++) {
        float hk = __shfl(h[k & 3], base | (k >> 2), 64);
#pragma unroll
        for (int i = 0; i < 4; i++) o[i] = fmaf(hk, sW2[k * HID + q * 4 + i], o[i]);
    }
#pragma unroll
    for (int i = 0; i < 4; i++) o[i] = fmaxf(o[i], 0.f);

    if (REDUCE) {
        if (!active) {
#pragma unroll
            for (int i = 0; i < 4; i++) o[i] = 0.f;
        }
#pragma unroll
        for (int i = 0; i < 4; i++) {
            float v = o[i];
            v += __shfl_xor(v, 8, 64);
            v += __shfl_xor(v, 16, 64);
            v += __shfl_xor(v, 32, 64);
            o[i] = v;
        }
        int wid = t >> 6;
        if (lane < 8) {
#pragma unroll
            for (int i = 0; i < 4; i++) red[wid][lane * 4 + i] = o[i];
        }
        __syncthreads();
        if (t < HID) {
            float s = red[0][t] + red[1][t] + red[2][t] + red[3][t];
            atomicAdd(&hsum[(blockIdx.x & (HS_ROWS - 1)) * (2 * HID) + t], s);
        }
    } else if (active) {
        unsigned pw = pack_e4(o[0], o[1], o[2], o[3]);
        *(unsigned*)(xout + ((size_t)node << 5) + (q << 2)) = pw;
    }
}

// ---------------- head ----------------
__global__ void head_kernel(const float* __restrict__ hsumP,
                            const float* __restrict__ Wc1, const float* __restrict__ bc1,
                            const float* __restrict__ Wc2, const float* __restrict__ bc2,
                            float* __restrict__ out) {
    __shared__ float hs[2 * HID];
    int t = threadIdx.x;
    if (t < 2 * HID) {
        float s = 0.f;
        for (int r = 0; r < HS_ROWS; r++) s += hsumP[r * (2 * HID) + t];
        hs[t] = s;
    }
    __syncthreads();
    float val = 0.f;
    if (t < HID) {
        float acc = bc1[t];
        for (int i = 0; i < 2 * HID; i++) acc = fmaf(hs[i], Wc1[i * HID + t], acc);
        val = fmaxf(acc, 0.f) * Wc2[t];
    }
    for (int off = 32; off >= 1; off >>= 1) val += __shfl_xor(val, off, 64);
    if (t == 0) out[0] = 1.f / (1.f + expf(-(val + bc2[0])));
}

extern "C" void kernel_launch(void* const* d_in, const int* in_sizes, int n_in,
                              void* d_out, int out_size, void* d_ws, size_t ws_size,
                              hipStream_t stream) {
    const float* xg[2] = { (const float*)d_in[0], (const float*)d_in[2] };
    const int*   eg[2] = { (const int*)d_in[1],   (const int*)d_in[3] };
    const float* W1[3] = { (const float*)d_in[4], (const float*)d_in[8],  (const float*)d_in[12] };
    const float* b1[3] = { (const float*)d_in[5], (const float*)d_in[9],  (const float*)d_in[13] };
    const float* W2[3] = { (const float*)d_in[6], (const float*)d_in[10], (const float*)d_in[14] };
    const float* b2[3] = { (const float*)d_in[7], (const float*)d_in[11], (const float*)d_in[15] };
    const float* Wc1 = (const float*)d_in[16];
    const float* bc1 = (const float*)d_in[17];
    const float* Wc2 = (const float*)d_in[18];
    const float* bc2 = (const float*)d_in[19];

    const int N = in_sizes[0];
    const int E = in_sizes[1] / 2;
    const int P = (N + NPB - 1) >> PSHIFT;   // 391 for N=100000

    const int TB = 256;
    dim3 blk(TB);
    int gE4k = (E + 4095) / 4096;
    int gN64 = (N + 63) / 64;
    int gN8  = (N + 31) / 32;

    // per-graph sizes (bytes)
    size_t szB    = (size_t)N * 32;                    // fp8 feature table
    size_t szRow  = (size_t)(N + 1) * 4;
    size_t szCol  = (size_t)E * 4;
    size_t szCb   = (size_t)(P + 1) * 4;
    size_t szGcur = (size_t)P * GS * 4;
    size_t szStg  = (size_t)P * SLOTS * 4;
    size_t szHsum = (size_t)HS_ROWS * 2 * HID * 4;
    size_t needBatched = 4 * szB + szHsum + 2 * (szRow + szCol + szCb + szGcur + szStg) + 4096;

    char* w = (char*)d_ws;
    auto take = [&](size_t sz) { char* p = w; w += (sz + 255) & ~(size_t)255; return p; };

    if (ws_size >= needBatched) {
        // ================= batched path: both graphs per dispatch =================
        u8*    B0[2]  = { (u8*)take(szB), (u8*)take(szB) };
        u8*    B1[2]  = { (u8*)take(szB), (u8*)take(szB) };
        float* hsumP  = (float*)take(szHsum);
        int*   rowp[2] = { (int*)take(szRow), (int*)take(szRow) };
        int*   col[2]  = { (int*)take(szCol), (int*)take(szCol) };
        int*   cb[2]   = { (int*)take(szCb), (int*)take(szCb) };
        int*   gc[2]   = { (int*)take(szGcur), (int*)take(szGcur) };
        unsigned* st[2] = { (unsigned*)take(szStg), (unsigned*)take(szStg) };

        zero_kernel<<<(HS_ROWS * 2 * HID + 255) / 256, 256, 0, stream>>>(hsumP, HS_ROWS * 2 * HID);
        init_gcur2<<<(2 * P + TB - 1) / TB, blk, 0, stream>>>(gc[0], gc[1], P);
        partition_edges<<<2 * gE4k, blk, 0, stream>>>(eg[0], eg[0] + E, gc[0], st[0],
                                                      eg[1], eg[1] + E, gc[1], st[1],
                                                      gE4k, E, P);
        scan_buckets<<<2, blk, 0, stream>>>(gc[0], cb[0], rowp[0], gc[1], cb[1], rowp[1], P, N);
        sort_bucket<<<2 * P, blk, 0, stream>>>(st[0], gc[0], cb[0], rowp[0], col[0],
                                               st[1], gc[1], cb[1], rowp[1], col[1], P, N);
        mlp0_fused<<<2 * gN64, blk, 0, stream>>>(rowp[0], col[0], xg[0], B0[0],
                                                 rowp[1], col[1], xg[1], B0[1],
                                                 W1[0], b1[0], W2[0], b2[0], gN64, N);
        mlp_fused<false><<<2 * gN8, blk, 0, stream>>>(rowp[0], col[0], B0[0], B1[0], nullptr,
                                                      rowp[1], col[1], B0[1], B1[1], nullptr,
                                                      W1[1], b1[1], W2[1], b2[1], gN8, N);
        mlp_fused<true><<<2 * gN8, blk, 0, stream>>>(rowp[0], col[0], B1[0], nullptr, hsumP,
                                                     rowp[1], col[1], B1[1], nullptr, hsumP + HID,
                                                     W1[2], b1[2], W2[2], b2[2], gN8, N);
        head_kernel<<<1, 64, 0, stream>>>(hsumP, Wc1, bc1, Wc2, bc2, (float*)d_out);
    } else {
        // ================= sequential fallback =================
        u8*    B0s    = (u8*)take(szB);
        u8*    B1s    = (u8*)take(szB);
        float* hsumP  = (float*)take(szHsum);
        int*   rowp   = (int*)take(szRow);
        int*   colp   = (int*)take(szCol);
        int*   cbp    = (int*)take(szCb);
        int*   gcp    = (int*)take(szGcur);
        unsigned* stp = (unsigned*)take(szStg);

        zero_kernel<<<(HS_ROWS * 2 * HID + 255) / 256, 256, 0, stream>>>(hsumP, HS_ROWS * 2 * HID);
        for (int g = 0; g < 2; g++) {
            const float* x0  = xg[g];
            const int*   src = eg[g];
            const int*   dst = src + E;
            init_gcur2<<<(P + TB - 1) / TB, blk, 0, stream>>>(gcp, gcp, P);
            partition_edges<<<gE4k, blk, 0, stream>>>(src, dst, gcp, stp,
                                                      src, dst, gcp, stp, gE4k, E, P);
            scan_buckets<<<1, blk, 0, stream>>>(gcp, cbp, rowp, gcp, cbp, rowp, P, N);
            sort_bucket<<<P, blk, 0, stream>>>(stp, gcp, cbp, rowp, colp,
                                               stp, gcp, cbp, rowp, colp, P, N);
            mlp0_fused<<<gN64, blk, 0, stream>>>(rowp, colp, x0, B0s,
                                                 rowp, colp, x0, B0s,
                                                 W1[0], b1[0], W2[0], b2[0], gN64, N);
            mlp_fused<false><<<gN8, blk, 0, stream>>>(rowp, colp, B0s, B1s, nullptr,
                                                      rowp, colp, B0s, B1s, nullptr,
                                                      W1[1], b1[1], W2[1], b2[1], gN8, N);
            mlp_fused<true><<<gN8, blk, 0, stream>>>(rowp, colp, B1s, nullptr, hsumP + g * HID,
                                                     rowp, colp, B1s, nullptr, hsumP + g * HID,
                                                     W1[2], b1[2], W2[2], b2[2], gN8, N);
        }
        head_kernel<<<1, 64, 0, stream>>>(hsumP, Wc1, bc1, Wc2, bc2, (float*)d_out);
    }
}

// Round 17
// 527.092 us; speedup vs baseline: 1.0475x; 1.0475x over previous
//
#include <hip/hip_runtime.h>
#include <hip/hip_bf16.h>
#include <math.h>
#include <string.h>

#define HID 32
#define PSHIFT 8                 // dst bucket = dst >> 8 (256 nodes/bucket)
#define NPB (1 << PSHIFT)
#define MAXP 512                 // partition scan width (supports N <= 131072)
#define SLOTS 17408              // per-bucket staging; mean 16384, +8 sigma (guarded)
#define GS 32                    // gcur stride in ints: 1 counter per 128B cacheline
#define HS_ROWS 32               // hsum partial rows (spread atomic contention)
#define COLBUF 3072              // mlp_fused col slice; 32 nodes, mean 2048 (guarded)
#define COLBUF0 6144             // mlp0 col slice; 64 nodes, mean 4096 (guarded)
typedef unsigned short u16;
typedef unsigned char u8;
typedef float f32x2 __attribute__((ext_vector_type(2)));

// ---------- fp8 e4m3 helpers (OCP; non-negative activations) ----------
__device__ inline float e42f_sw(unsigned b) {
    unsigned u = (b & 0x7fu) << 20;
    float f; memcpy(&f, &u, 4);
    return f * 0x1p120f;
}
__device__ inline unsigned f2e4_sw(float f) {
    f = fminf(f, 448.f);
    float y = f * 0x1p-120f;
    unsigned r; memcpy(&r, &y, 4);
    r = r + 0x7FFFFu + ((r >> 20) & 1u);
    return (r >> 20) & 0x7fu;
}
__device__ inline void acc_e4(float* a, unsigned w) {
#if __has_builtin(__builtin_amdgcn_cvt_pk_f32_fp8)
    f32x2 lo = __builtin_amdgcn_cvt_pk_f32_fp8(w, false);
    f32x2 hi = __builtin_amdgcn_cvt_pk_f32_fp8(w, true);
    a[0] += lo.x; a[1] += lo.y; a[2] += hi.x; a[3] += hi.y;
#else
    a[0] += e42f_sw(w);
    a[1] += e42f_sw(w >> 8);
    a[2] += e42f_sw(w >> 16);
    a[3] += e42f_sw(w >> 24);
#endif
}
__device__ inline unsigned pack_e4(float o0, float o1, float o2, float o3) {
#if __has_builtin(__builtin_amdgcn_cvt_pk_fp8_f32)
    unsigned pw = (unsigned)__builtin_amdgcn_cvt_pk_fp8_f32(
        fminf(o0, 448.f), fminf(o1, 448.f), 0, false);
    pw = (unsigned)__builtin_amdgcn_cvt_pk_fp8_f32(
        fminf(o2, 448.f), fminf(o3, 448.f), pw, true);
    return pw;
#else
    return f2e4_sw(o0) | (f2e4_sw(o1) << 8) | (f2e4_sw(o2) << 16) | (f2e4_sw(o3) << 24);
#endif
}

// ---------------- zero / init ----------------
__global__ void zero_kernel(float* __restrict__ p, int n) {
    int i = blockIdx.x * blockDim.x + threadIdx.x;
    if (i < n) p[i] = 0.f;
}
__global__ void init_gcur2(int* __restrict__ gA, int* __restrict__ gB, int P) {
    int i = blockIdx.x * blockDim.x + threadIdx.x;
    if (i < P) gA[i * GS] = i * SLOTS;
    else if (i < 2 * P) { int b = i - P; gB[b * GS] = b * SLOTS; }
}

// ---------------- phase 1: partition (R7 core, graph-batched grid) ----------------
// R12/R14/R16 lesson (x3): the LDS sortedv staging IS the write-coalescing
// mechanism — placement scatters into LDS, writeout is coalesced linear runs.
// R16's register-direct store (no staging) scattered 4B writes: 113->139MB, +25us.
__global__ void partition_edges(const int* __restrict__ srcA, const int* __restrict__ dstA,
                                int* __restrict__ gcurA, unsigned* __restrict__ stagedA,
                                const int* __restrict__ srcB, const int* __restrict__ dstB,
                                int* __restrict__ gcurB, unsigned* __restrict__ stagedB,
                                int gsplit, int E, int P) {
    __shared__ int h[4][MAXP];
    __shared__ int hbase[MAXP];
    __shared__ int cur[MAXP];
    __shared__ int gbase[MAXP];
    __shared__ unsigned sortedv[4096];
    __shared__ u16 bktid[4096];
    __shared__ int wsums[4];
    __shared__ int sTotal;
    const int* src; const int* dst; int* gcur; unsigned* staged;
    int bid = blockIdx.x;
    if (bid < gsplit) { src = srcA; dst = dstA; gcur = gcurA; staged = stagedA; }
    else { bid -= gsplit; src = srcB; dst = dstB; gcur = gcurB; staged = stagedB; }

    int t = threadIdx.x, wid = t >> 6, lane = t & 63;
    for (int i = t; i < 4 * MAXP; i += 256) (&h[0][0])[i] = 0;
    __syncthreads();

    int base = bid * 4096;
    int4 S[4], D[4];
#pragma unroll
    for (int r = 0; r < 4; r++) {
        int e = base + r * 1024 + t * 4;
        if (e + 3 < E) {
            S[r] = *(const int4*)(src + e);
            D[r] = *(const int4*)(dst + e);
        } else {
            int s0[4], d0[4];
            for (int j = 0; j < 4; j++) {
                int ee = e + j;
                s0[j] = (ee < E) ? src[ee] : -1;
                d0[j] = (ee < E) ? dst[ee] : -1;
            }
            S[r] = make_int4(s0[0], s0[1], s0[2], s0[3]);
            D[r] = make_int4(d0[0], d0[1], d0[2], d0[3]);
        }
        if (D[r].x >= 0) atomicAdd(&h[wid][D[r].x >> PSHIFT], 1);
        if (D[r].y >= 0) atomicAdd(&h[wid][D[r].y >> PSHIFT], 1);
        if (D[r].z >= 0) atomicAdd(&h[wid][D[r].z >> PSHIFT], 1);
        if (D[r].w >= 0) atomicAdd(&h[wid][D[r].w >> PSHIFT], 1);
    }
    __syncthreads();

    int b0 = 2 * t, b1 = 2 * t + 1;
    int t0 = (b0 < P) ? (h[0][b0] + h[1][b0] + h[2][b0] + h[3][b0]) : 0;
    int t1 = (b1 < P) ? (h[0][b1] + h[1][b1] + h[2][b1] + h[3][b1]) : 0;
    int s = t0 + t1;
    int incl = s;
#pragma unroll
    for (int off = 1; off < 64; off <<= 1) {
        int u = __shfl_up(incl, off, 64);
        if (lane >= off) incl += u;
    }
    if (lane == 63) wsums[wid] = incl;
    __syncthreads();
    int woff = 0;
#pragma unroll
    for (int w = 0; w < 4; w++) if (w < wid) woff += wsums[w];
    int excl = woff + incl - s;
    if (b0 < P) { hbase[b0] = excl;      cur[b0] = excl; }
    if (b1 < P) { hbase[b1] = excl + t0; cur[b1] = excl + t0; }
    if (b0 < P && t0) gbase[b0] = atomicAdd(&gcur[b0 * GS], t0);
    if (b1 < P && t1) gbase[b1] = atomicAdd(&gcur[b1 * GS], t1);
    if (t == 255) sTotal = excl + s;
    __syncthreads();

#pragma unroll
    for (int r = 0; r < 4; r++) {
        int ss[4] = { S[r].x, S[r].y, S[r].z, S[r].w };
        int dd[4] = { D[r].x, D[r].y, D[r].z, D[r].w };
#pragma unroll
        for (int j = 0; j < 4; j++) {
            int d = dd[j];
            if (d >= 0) {
                int bk = d >> PSHIFT;
                int pos = atomicAdd(&cur[bk], 1);
                sortedv[pos] = ((unsigned)(d & (NPB - 1)) << 17) | (unsigned)ss[j];
                bktid[pos]   = (u16)bk;
            }
        }
    }
    __syncthreads();

    int total = sTotal;
    for (int i = t; i < total; i += 256) {
        int bk = bktid[i];
        int addr = gbase[bk] + (i - hbase[bk]);
        if (addr < (bk + 1) * SLOTS)
            staged[addr] = sortedv[i];
    }
}

// ---------------- phase 2: bucket-count scan; block per graph ----------------
__global__ void scan_buckets(const int* __restrict__ gcurA, int* __restrict__ colbaseA,
                             int* __restrict__ rowptrA,
                             const int* __restrict__ gcurB, int* __restrict__ colbaseB,
                             int* __restrict__ rowptrB, int P, int N) {
    __shared__ int wsums[4];
    const int* gcur; int* colbase; int* rowptr;
    if (blockIdx.x == 0) { gcur = gcurA; colbase = colbaseA; rowptr = rowptrA; }
    else { gcur = gcurB; colbase = colbaseB; rowptr = rowptrB; }
    int t = threadIdx.x, wid = t >> 6, lane = t & 63;
    int b0 = 2 * t, b1 = 2 * t + 1;
    int c0 = 0, c1 = 0;
    if (b0 < P) { c0 = gcur[b0 * GS] - b0 * SLOTS; if (c0 > SLOTS) c0 = SLOTS; }
    if (b1 < P) { c1 = gcur[b1 * GS] - b1 * SLOTS; if (c1 > SLOTS) c1 = SLOTS; }
    int s = c0 + c1;
    int incl = s;
#pragma unroll
    for (int off = 1; off < 64; off <<= 1) {
        int u = __shfl_up(incl, off, 64);
        if (lane >= off) incl += u;
    }
    if (lane == 63) wsums[wid] = incl;
    __syncthreads();
    int woff = 0;
#pragma unroll
    for (int w = 0; w < 4; w++) if (w < wid) woff += wsums[w];
    int excl = woff + incl - s;
    if (b0 < P) colbase[b0] = excl;
    if (b1 < P) colbase[b1] = excl + c0;
    if (t == 255) {
        colbase[P] = excl + s;
        rowptr[N]  = excl + s;
    }
}

// ---------------- phase 3: per-bucket counting sort, LDS-staged writeout ---------
// R15: dst_local-only key; LDS sorted[] staging so the col writeout is CONTIGUOUS.
__global__ void sort_bucket(const unsigned* __restrict__ stagedA, const int* __restrict__ gcurA,
                            const int* __restrict__ colbaseA, int* __restrict__ rowptrA,
                            int* __restrict__ colA,
                            const unsigned* __restrict__ stagedB, const int* __restrict__ gcurB,
                            const int* __restrict__ colbaseB, int* __restrict__ rowptrB,
                            int* __restrict__ colB,
                            int gsplit, int N) {
    __shared__ int cnt[NPB];            // 1 KB
    __shared__ int wsum[4];
    __shared__ int sorted[SLOTS];       // 68 KB
    const unsigned* staged; const int* gcur; const int* colbase; int* rowptr; int* col;
    int b = blockIdx.x;
    if (b < gsplit) { staged = stagedA; gcur = gcurA; colbase = colbaseA; rowptr = rowptrA; col = colA; }
    else { b -= gsplit; staged = stagedB; gcur = gcurB; colbase = colbaseB; rowptr = rowptrB; col = colB; }
    int t = threadIdx.x, lane = t & 63, wid = t >> 6;
    int sBeg = b * SLOTS;
    int sEnd = gcur[b * GS]; if (sEnd > sBeg + SLOTS) sEnd = sBeg + SLOTS;
    int total = sEnd - sBeg;
    int colStart = colbase[b];
    int nodeBase = b << PSHIFT;

    cnt[t] = 0;                          // NPB == 256 == blockDim
    __syncthreads();
    for (int i = sBeg + t; i < sEnd; i += 256)
        atomicAdd(&cnt[staged[i] >> 17], 1);
    __syncthreads();

    int myc = cnt[t];
    int incl = myc;
#pragma unroll
    for (int off = 1; off < 64; off <<= 1) {
        int u = __shfl_up(incl, off, 64);
        if (lane >= off) incl += u;
    }
    if (lane == 63) wsum[wid] = incl;
    __syncthreads();
    int woff = 0;
#pragma unroll
    for (int w = 0; w < 4; w++) if (w < wid) woff += wsum[w];
    int excl = woff + incl - myc;
    int node = nodeBase + t;
    if (node < N) rowptr[node] = colStart + excl;
    __syncthreads();
    cnt[t] = excl;                       // LDS placement cursor for node t
    __syncthreads();

    for (int i = sBeg + t; i < sEnd; i += 256) {
        unsigned w = staged[i];
        int pos = atomicAdd(&cnt[w >> 17], 1);
        sorted[pos] = (int)(w & 0x1FFFFu);
    }
    __syncthreads();
    for (int i = t; i < total; i += 256)   // contiguous coalesced writeout
        col[colStart + i] = sorted[i];
}

// ---------------- layer 0 fused: gather(d=1) + MLP -> fp8 out (graph-batched) -----
__global__ void mlp0_fused(const int* __restrict__ rowptrA, const int* __restrict__ colA,
                           const float* __restrict__ x0A, u8* __restrict__ outA,
                           const int* __restrict__ rowptrB, const int* __restrict__ colB,
                           const float* __restrict__ x0B, u8* __restrict__ outB,
                           const float* __restrict__ W1, const float* __restrict__ b1,
                           const float* __restrict__ W2, const float* __restrict__ b2,
                           int gsplit, int n) {
    __shared__ float sW1[HID], sb1[HID], sW2[HID * HID], sb2[HID];
    __shared__ int colbuf[COLBUF0];
    const int* rowptr; const int* col; const float* x0; u8* out;
    int bid = blockIdx.x;
    if (bid < gsplit) { rowptr = rowptrA; col = colA; x0 = x0A; out = outA; }
    else { bid -= gsplit; rowptr = rowptrB; col = colB; x0 = x0B; out = outB; }
    int t = threadIdx.x;
    if (t < HID) { sW1[t] = W1[t]; sb1[t] = b1[t]; sb2[t] = b2[t]; }
    for (int i = t; i < HID * HID; i += blockDim.x) sW2[i] = W2[i];

    int firstNode = bid * 64;
    int lastNode  = firstNode + 64; if (lastNode > n) lastNode = n;
    int blockStart = (firstNode < n) ? rowptr[firstNode] : 0;
    int blockEnd   = (firstNode < n) ? rowptr[lastNode] : 0;
    int stagedCnt = blockEnd - blockStart; if (stagedCnt > COLBUF0) stagedCnt = COLBUF0;
    for (int i = t; i < stagedCnt; i += 256) colbuf[i] = col[blockStart + i];
    __syncthreads();

    int node = firstNode + (t >> 2);
    int q    = t & 3;
    int lane = t & 63;
    int base = lane & ~3;
    bool active = node < n;

    float s = 0.f;
    if (active) {
        int beg = rowptr[node], end = rowptr[node + 1];
        int jSplit = blockStart + stagedCnt; if (jSplit > end) jSplit = end;
        int j = beg + q;
        for (; j + 12 < jSplit; j += 16) {
            int c0 = colbuf[j - blockStart];
            int c1 = colbuf[j + 4 - blockStart];
            int c2 = colbuf[j + 8 - blockStart];
            int c3 = colbuf[j + 12 - blockStart];
            s += x0[c0]; s += x0[c1]; s += x0[c2]; s += x0[c3];
        }
        for (; j < jSplit; j += 4) s += x0[colbuf[j - blockStart]];
        for (; j < end; j += 4) s += x0[col[j]];
    }
    s += __shfl_xor(s, 1, 64);
    s += __shfl_xor(s, 2, 64);
    float v = active ? (x0[node] + s) : 0.f;

    float h[8];
#pragma unroll
    for (int i = 0; i < 8; i++) h[i] = fmaxf(fmaf(v, sW1[q * 8 + i], sb1[q * 8 + i]), 0.f);
    float o[8];
#pragma unroll
    for (int i = 0; i < 8; i++) o[i] = sb2[q * 8 + i];
#pragma unroll
    for (int k = 0; k < HID; k++) {
        float hk = __shfl(h[k & 7], base | (k >> 3), 64);
#pragma unroll
        for (int i = 0; i < 8; i++) o[i] = fmaf(hk, sW2[k * HID + q * 8 + i], o[i]);
    }
    if (active) {
        unsigned w0 = pack_e4(fmaxf(o[0], 0.f), fmaxf(o[1], 0.f),
                              fmaxf(o[2], 0.f), fmaxf(o[3], 0.f));
        unsigned w1 = pack_e4(fmaxf(o[4], 0.f), fmaxf(o[5], 0.f),
                              fmaxf(o[6], 0.f), fmaxf(o[7], 0.f));
        uint2 pk = make_uint2(w0, w1);
        *(uint2*)(out + ((size_t)node << 5) + (q << 3)) = pk;
    }
}

// ---------------- hidden layer fused: fp8 gather + MLP (graph-batched) ----------
template <bool REDUCE>
__global__ void mlp_fused(const int* __restrict__ rowptrA, const int* __restrict__ colA,
                          const u8* __restrict__ xinA, u8* __restrict__ xoutA,
                          float* __restrict__ hsumA,
                          const int* __restrict__ rowptrB, const int* __restrict__ colB,
                          const u8* __restrict__ xinB, u8* __restrict__ xoutB,
                          float* __restrict__ hsumB,
                          const float* __restrict__ W1, const float* __restrict__ b1,
                          const float* __restrict__ W2, const float* __restrict__ b2,
                          int gsplit, int n) {
    __shared__ float sW1[HID * HID], sb1[HID], sW2[HID * HID], sb2[HID];
    __shared__ int colbuf[COLBUF];
    __shared__ float red[4][HID];
    const int* rowptr; const int* col; const u8* xin; u8* xout; float* hsum;
    int bid = blockIdx.x;
    if (bid < gsplit) { rowptr = rowptrA; col = colA; xin = xinA; xout = xoutA; hsum = hsumA; }
    else { bid -= gsplit; rowptr = rowptrB; col = colB; xin = xinB; xout = xoutB; hsum = hsumB; }
    int t = threadIdx.x;
    for (int i = t; i < HID * HID; i += blockDim.x) { sW1[i] = W1[i]; sW2[i] = W2[i]; }
    if (t < HID) { sb1[t] = b1[t]; sb2[t] = b2[t]; }

    int firstNode = bid * 32;
    int lastNode  = firstNode + 32; if (lastNode > n) lastNode = n;
    int blockStart = (firstNode < n) ? rowptr[firstNode] : 0;
    int blockEnd   = (firstNode < n) ? rowptr[lastNode] : 0;
    int stagedCnt = blockEnd - blockStart; if (stagedCnt > COLBUF) stagedCnt = COLBUF;
    for (int i = t; i < stagedCnt; i += 256) colbuf[i] = col[blockStart + i];
    __syncthreads();

    int node = firstNode + (t >> 3);
    int q    = t & 7;
    int lane = t & 63;
    int base = lane & ~7;
    bool active = node < n;

    float va[4];
#pragma unroll
    for (int i = 0; i < 4; i++) va[i] = 0.f;
    if (active) {
        int beg = rowptr[node], end = rowptr[node + 1];
        const u8* xq = xin + (q << 2);
        float a0[4], a1[4], a2[4], a3[4];
#pragma unroll
        for (int i = 0; i < 4; i++) a0[i] = a1[i] = a2[i] = a3[i] = 0.f;
        {   // self term (eps = 0)
            unsigned w = *(const unsigned*)(xq + ((size_t)node << 5));
            acc_e4(a0, w);
        }
        int jSplit = blockStart + stagedCnt; if (jSplit > end) jSplit = end;
        int j = beg;
        for (; j + 8 <= jSplit; j += 8) {
            int lj = j - blockStart;
            int c0 = colbuf[lj+0], c1 = colbuf[lj+1], c2 = colbuf[lj+2], c3 = colbuf[lj+3];
            int c4 = colbuf[lj+4], c5 = colbuf[lj+5], c6 = colbuf[lj+6], c7 = colbuf[lj+7];
            unsigned w0 = *(const unsigned*)(xq + ((size_t)c0 << 5));
            unsigned w1 = *(const unsigned*)(xq + ((size_t)c1 << 5));
            unsigned w2 = *(const unsigned*)(xq + ((size_t)c2 << 5));
            unsigned w3 = *(const unsigned*)(xq + ((size_t)c3 << 5));
            unsigned w4 = *(const unsigned*)(xq + ((size_t)c4 << 5));
            unsigned w5 = *(const unsigned*)(xq + ((size_t)c5 << 5));
            unsigned w6 = *(const unsigned*)(xq + ((size_t)c6 << 5));
            unsigned w7 = *(const unsigned*)(xq + ((size_t)c7 << 5));
            acc_e4(a0, w0); acc_e4(a1, w1); acc_e4(a2, w2); acc_e4(a3, w3);
            acc_e4(a0, w4); acc_e4(a1, w5); acc_e4(a2, w6); acc_e4(a3, w7);
        }
        for (; j < jSplit; j++) {
            unsigned w = *(const unsigned*)(xq + ((size_t)colbuf[j - blockStart] << 5));
            acc_e4(a0, w);
        }
        for (; j < end; j++) {
            unsigned w = *(const unsigned*)(xq + ((size_t)col[j] << 5));
            acc_e4(a0, w);
        }
#pragma unroll
        for (int i = 0; i < 4; i++) va[i] = (a0[i] + a1[i]) + (a2[i] + a3[i]);
    }

    float h[4];
#pragma unroll
    for (int i = 0; i < 4; i++) h[i] = sb1[q * 4 + i];
#pragma unroll
    for (int k = 0; k < HID; k++) {
        float vk = __shfl(va[k & 3], base | (k >> 2), 64);
#pragma unroll
        for (int i = 0; i < 4; i++) h[i] = fmaf(vk, sW1[k * HID + q * 4 + i], h[i]);
    }
#pragma unroll
    for (int i = 0; i < 4; i++) h[i] = fmaxf(h[i], 0.f);

    float o[4];
#pragma unroll
    for (int i = 0; i < 4; i++) o[i] = sb2[q * 4 + i];
#pragma unroll
    for (int k = 0; k < HID; k++) {
        float hk = __shfl(h[k & 3], base | (k >> 2), 64);
#pragma unroll
        for (int i = 0; i < 4; i++) o[i] = fmaf(hk, sW2[k * HID + q * 4 + i], o[i]);
    }
#pragma unroll
    for (int i = 0; i < 4; i++) o[i] = fmaxf(o[i], 0.f);

    if (REDUCE) {
        if (!active) {
#pragma unroll
            for (int i = 0; i < 4; i++) o[i] = 0.f;
        }
#pragma unroll
        for (int i = 0; i < 4; i++) {
            float v = o[i];
            v += __shfl_xor(v, 8, 64);
            v += __shfl_xor(v, 16, 64);
            v += __shfl_xor(v, 32, 64);
            o[i] = v;
        }
        int wid = t >> 6;
        if (lane < 8) {
#pragma unroll
            for (int i = 0; i < 4; i++) red[wid][lane * 4 + i] = o[i];
        }
        __syncthreads();
        if (t < HID) {
            float s = red[0][t] + red[1][t] + red[2][t] + red[3][t];
            atomicAdd(&hsum[(blockIdx.x & (HS_ROWS - 1)) * (2 * HID) + t], s);
        }
    } else if (active) {
        unsigned pw = pack_e4(o[0], o[1], o[2], o[3]);
        *(unsigned*)(xout + ((size_t)node << 5) + (q << 2)) = pw;
    }
}

// ---------------- head ----------------
__global__ void head_kernel(const float* __restrict__ hsumP,
                            const float* __restrict__ Wc1, const float* __restrict__ bc1,
                            const float* __restrict__ Wc2, const float* __restrict__ bc2,
                            float* __restrict__ out) {
    __shared__ float hs[2 * HID];
    int t = threadIdx.x;
    if (t < 2 * HID) {
        float s = 0.f;
        for (int r = 0; r < HS_ROWS; r++) s += hsumP[r * (2 * HID) + t];
        hs[t] = s;
    }
    __syncthreads();
    float val = 0.f;
    if (t < HID) {
        float acc = bc1[t];
        for (int i = 0; i < 2 * HID; i++) acc = fmaf(hs[i], Wc1[i * HID + t], acc);
        val = fmaxf(acc, 0.f) * Wc2[t];
    }
    for (int off = 32; off >= 1; off >>= 1) val += __shfl_xor(val, off, 64);
    if (t == 0) out[0] = 1.f / (1.f + expf(-(val + bc2[0])));
}

extern "C" void kernel_launch(void* const* d_in, const int* in_sizes, int n_in,
                              void* d_out, int out_size, void* d_ws, size_t ws_size,
                              hipStream_t stream) {
    const float* xg[2] = { (const float*)d_in[0], (const float*)d_in[2] };
    const int*   eg[2] = { (const int*)d_in[1],   (const int*)d_in[3] };
    const float* W1[3] = { (const float*)d_in[4], (const float*)d_in[8],  (const float*)d_in[12] };
    const float* b1[3] = { (const float*)d_in[5], (const float*)d_in[9],  (const float*)d_in[13] };
    const float* W2[3] = { (const float*)d_in[6], (const float*)d_in[10], (const float*)d_in[14] };
    const float* b2[3] = { (const float*)d_in[7], (const float*)d_in[11], (const float*)d_in[15] };
    const float* Wc1 = (const float*)d_in[16];
    const float* bc1 = (const float*)d_in[17];
    const float* Wc2 = (const float*)d_in[18];
    const float* bc2 = (const float*)d_in[19];

    const int N = in_sizes[0];
    const int E = in_sizes[1] / 2;
    const int P = (N + NPB - 1) >> PSHIFT;   // 391 for N=100000

    const int TB = 256;
    dim3 blk(TB);
    int gE4k = (E + 4095) / 4096;
    int gN64 = (N + 63) / 64;
    int gN8  = (N + 31) / 32;

    // per-graph sizes (bytes)
    size_t szB    = (size_t)N * 32;                    // fp8 feature table
    size_t szRow  = (size_t)(N + 1) * 4;
    size_t szCol  = (size_t)E * 4;
    size_t szCb   = (size_t)(P + 1) * 4;
    size_t szGcur = (size_t)P * GS * 4;
    size_t szStg  = (size_t)P * SLOTS * 4;
    size_t szHsum = (size_t)HS_ROWS * 2 * HID * 4;
    size_t needBatched = 4 * szB + szHsum + 2 * (szRow + szCol + szCb + szGcur + szStg) + 4096;

    char* w = (char*)d_ws;
    auto take = [&](size_t sz) { char* p = w; w += (sz + 255) & ~(size_t)255; return p; };

    if (ws_size >= needBatched) {
        // ================= batched path: both graphs per dispatch =================
        u8*    B0[2]  = { (u8*)take(szB), (u8*)take(szB) };
        u8*    B1[2]  = { (u8*)take(szB), (u8*)take(szB) };
        float* hsumP  = (float*)take(szHsum);
        int*   rowp[2] = { (int*)take(szRow), (int*)take(szRow) };
        int*   col[2]  = { (int*)take(szCol), (int*)take(szCol) };
        int*   cb[2]   = { (int*)take(szCb), (int*)take(szCb) };
        int*   gc[2]   = { (int*)take(szGcur), (int*)take(szGcur) };
        unsigned* st[2] = { (unsigned*)take(szStg), (unsigned*)take(szStg) };

        zero_kernel<<<(HS_ROWS * 2 * HID + 255) / 256, 256, 0, stream>>>(hsumP, HS_ROWS * 2 * HID);
        init_gcur2<<<(2 * P + TB - 1) / TB, blk, 0, stream>>>(gc[0], gc[1], P);
        partition_edges<<<2 * gE4k, blk, 0, stream>>>(eg[0], eg[0] + E, gc[0], st[0],
                                                      eg[1], eg[1] + E, gc[1], st[1],
                                                      gE4k, E, P);
        scan_buckets<<<2, blk, 0, stream>>>(gc[0], cb[0], rowp[0], gc[1], cb[1], rowp[1], P, N);
        sort_bucket<<<2 * P, blk, 0, stream>>>(st[0], gc[0], cb[0], rowp[0], col[0],
                                               st[1], gc[1], cb[1], rowp[1], col[1], P, N);
        mlp0_fused<<<2 * gN64, blk, 0, stream>>>(rowp[0], col[0], xg[0], B0[0],
                                                 rowp[1], col[1], xg[1], B0[1],
                                                 W1[0], b1[0], W2[0], b2[0], gN64, N);
        mlp_fused<false><<<2 * gN8, blk, 0, stream>>>(rowp[0], col[0], B0[0], B1[0], nullptr,
                                                      rowp[1], col[1], B0[1], B1[1], nullptr,
                                                      W1[1], b1[1], W2[1], b2[1], gN8, N);
        mlp_fused<true><<<2 * gN8, blk, 0, stream>>>(rowp[0], col[0], B1[0], nullptr, hsumP,
                                                     rowp[1], col[1], B1[1], nullptr, hsumP + HID,
                                                     W1[2], b1[2], W2[2], b2[2], gN8, N);
        head_kernel<<<1, 64, 0, stream>>>(hsumP, Wc1, bc1, Wc2, bc2, (float*)d_out);
    } else {
        // ================= sequential fallback =================
        u8*    B0s    = (u8*)take(szB);
        u8*    B1s    = (u8*)take(szB);
        float* hsumP  = (float*)take(szHsum);
        int*   rowp   = (int*)take(szRow);
        int*   colp   = (int*)take(szCol);
        int*   cbp    = (int*)take(szCb);
        int*   gcp    = (int*)take(szGcur);
        unsigned* stp = (unsigned*)take(szStg);

        zero_kernel<<<(HS_ROWS * 2 * HID + 255) / 256, 256, 0, stream>>>(hsumP, HS_ROWS * 2 * HID);
        for (int g = 0; g < 2; g++) {
            const float* x0  = xg[g];
            const int*   src = eg[g];
            const int*   dst = src + E;
            init_gcur2<<<(P + TB - 1) / TB, blk, 0, stream>>>(gcp, gcp, P);
            partition_edges<<<gE4k, blk, 0, stream>>>(src, dst, gcp, stp,
                                                      src, dst, gcp, stp, gE4k, E, P);
            scan_buckets<<<1, blk, 0, stream>>>(gcp, cbp, rowp, gcp, cbp, rowp, P, N);
            sort_bucket<<<P, blk, 0, stream>>>(stp, gcp, cbp, rowp, colp,
                                               stp, gcp, cbp, rowp, colp, P, N);
            mlp0_fused<<<gN64, blk, 0, stream>>>(rowp, colp, x0, B0s,
                                                 rowp, colp, x0, B0s,
                                                 W1[0], b1[0], W2[0], b2[0], gN64, N);
            mlp_fused<false><<<gN8, blk, 0, stream>>>(rowp, colp, B0s, B1s, nullptr,
                                                      rowp, colp, B0s, B1s, nullptr,
                                                      W1[1], b1[1], W2[1], b2[1], gN8, N);
            mlp_fused<true><<<gN8, blk, 0, stream>>>(rowp, colp, B1s, nullptr, hsumP + g * HID,
                                                     rowp, colp, B1s, nullptr, hsumP + g * HID,
                                                     W1[2], b1[2], W2[2], b2[2], gN8, N);
        }
        head_kernel<<<1, 64, 0, stream>>>(hsumP, Wc1, bc1, Wc2, bc2, (float*)d_out);
    }
}